// Round 14
// baseline (643.995 us; speedup 1.0000x reference)
//
#include <hip/hip_runtime.h>
#include <hip/hip_bf16.h>

#define F_IN   128
#define HID    64
#define HEADS  4
#define OUTD   10
#define NGRP   64

typedef unsigned short u16;
typedef __attribute__((ext_vector_type(8))) short short8;
typedef __attribute__((ext_vector_type(4))) float f32x4;

__device__ __forceinline__ float atomAddF(float* p, float v) {
    return __hip_atomic_fetch_add(p, v, __ATOMIC_RELAXED, __HIP_MEMORY_SCOPE_AGENT);
}
__device__ __forceinline__ float lrelu(float f) { return f > 0.f ? f : 0.2f * f; }
__device__ __forceinline__ float b2f(u16 u) { return __uint_as_float(((unsigned)u) << 16); }
__device__ __forceinline__ u16 f2b(float f) {  // RNE
    unsigned u = __float_as_uint(f);
    return (u16)((u + 0x7fffu + ((u >> 16) & 1u)) >> 16);
}
__device__ __forceinline__ unsigned fmono(float f) {
    unsigned u = __float_as_uint(f);
    return (u & 0x80000000u) ? ~u : (u | 0x80000000u);
}
__device__ __forceinline__ float funmono(unsigned u) {
    return __uint_as_float((u & 0x80000000u) ? (u & 0x7FFFFFFFu) : ~u);
}

// ---------------- all three W[K][NC] fp32 -> Wt[NC][K] bf16, one kernel
__global__ __launch_bounds__(256) void wtrans_all_kernel(const float* __restrict__ W1,
                                                         const float* __restrict__ W2,
                                                         const float* __restrict__ W3,
                                                         u16* __restrict__ Wt1,
                                                         u16* __restrict__ Wt2,
                                                         u16* __restrict__ Wt3) {
    int i = blockIdx.x * 256 + threadIdx.x;
    if (i < 32768) {                       // W1: K=128, NC=256
        int n = i >> 7, k = i & 127;
        Wt1[i] = f2b(W1[(size_t)k * 256 + n]);
    } else if (i < 98304) {                // W2: K=256, NC=256
        int j = i - 32768;
        int n = j >> 8, k = j & 255;
        Wt2[j] = f2b(W2[(size_t)k * 256 + n]);
    } else if (i < 114688) {               // W3: K=256, NC=64
        int j = i - 98304;
        int n = j >> 8, k = j & 255;
        Wt3[j] = f2b(W3[(size_t)k * 64 + n]);   // W3 row stride is 64
    }
}

// ---------------- bf16 MFMA GEMM with fused attention-score epilogue.
// BM=128, 512 threads (8 waves).
// NC==256: waves arranged 2 row-groups x 4 col-groups; col-group == head.
// NC==64 : wave w owns rows [16w,16w+16) x all 64 cols; single head.
template<int K, int NC, bool AF32>
__global__ __launch_bounds__(512) void gemm_att_kernel(const void* __restrict__ Aptr,
                                                       const u16* __restrict__ Bt,
                                                       const float* __restrict__ as_,
                                                       const float* __restrict__ ad_,
                                                       u16* __restrict__ Hb,
                                                       float* __restrict__ a_src,
                                                       float* __restrict__ a_dst,
                                                       int nrows) {
    constexpr int LDA = 40;  // bf16 elems/row incl pad: 80B stride, 16B aligned
    constexpr int HH = NC / 64;
    __shared__ u16 As[128][LDA];
    __shared__ u16 Bs[NC][LDA];
    int tid = threadIdx.x;
    int m0 = blockIdx.x * 128;
    int w = tid >> 6, l = tid & 63, lr = l & 15, lk = l >> 4;

    if constexpr (NC == 256) {
        int wr = w >> 2, wc = w & 3;   // row-group, col-group(=head)
        f32x4 acc[4][4] = {};
        for (int k0 = 0; k0 < K; k0 += 32) {
            {   // stage A tile 128x32: one short8 per thread
                int row = tid >> 2, ks = (tid & 3) * 8;
                int grow = m0 + row;
                short8 av = {};
                if (grow < nrows) {
                    if constexpr (AF32) {
                        const float* src = (const float*)Aptr + (size_t)grow * K + k0 + ks;
                        float4 v0 = *(const float4*)src;
                        float4 v1 = *(const float4*)(src + 4);
                        av[0] = (short)f2b(v0.x); av[1] = (short)f2b(v0.y);
                        av[2] = (short)f2b(v0.z); av[3] = (short)f2b(v0.w);
                        av[4] = (short)f2b(v1.x); av[5] = (short)f2b(v1.y);
                        av[6] = (short)f2b(v1.z); av[7] = (short)f2b(v1.w);
                    } else {
                        av = *(const short8*)&((const u16*)Aptr)[(size_t)grow * K + k0 + ks];
                    }
                }
                *(short8*)&As[row][ks] = av;
            }
            #pragma unroll
            for (int i = 0; i < 2; i++) {  // stage B tile 256x32: two short8 per thread
                int col = (tid >> 2) + 128 * i;
                int ks = (tid & 3) * 8;
                *(short8*)&Bs[col][ks] = *(const short8*)&Bt[(size_t)col * K + k0 + ks];
            }
            __syncthreads();
            short8 a[4], b[4];
            #pragma unroll
            for (int mi = 0; mi < 4; mi++) a[mi] = *(const short8*)&As[64 * wr + 16 * mi + lr][lk * 8];
            #pragma unroll
            for (int ni = 0; ni < 4; ni++) b[ni] = *(const short8*)&Bs[64 * wc + 16 * ni + lr][lk * 8];
            #pragma unroll
            for (int mi = 0; mi < 4; mi++)
                #pragma unroll
                for (int ni = 0; ni < 4; ni++)
                    acc[mi][ni] = __builtin_amdgcn_mfma_f32_16x16x32_bf16(a[mi], b[ni], acc[mi][ni], 0, 0, 0);
            __syncthreads();
        }
        // C write
        #pragma unroll
        for (int mi = 0; mi < 4; mi++) {
            #pragma unroll
            for (int j = 0; j < 4; j++) {
                int grow = m0 + 64 * wr + 16 * mi + lk * 4 + j;
                if (grow < nrows) {
                    #pragma unroll
                    for (int ni = 0; ni < 4; ni++)
                        Hb[(size_t)grow * NC + 64 * wc + 16 * ni + lr] = f2b(acc[mi][ni][j]);
                }
            }
        }
        // attention epilogue: col-group wc == head wc; col within head = 16*ni + lr
        float asv[4], adv[4];
        #pragma unroll
        for (int ni = 0; ni < 4; ni++) {
            asv[ni] = as_[wc * 64 + 16 * ni + lr];
            adv[ni] = ad_[wc * 64 + 16 * ni + lr];
        }
        #pragma unroll
        for (int mi = 0; mi < 4; mi++) {
            #pragma unroll
            for (int j = 0; j < 4; j++) {
                float ps = 0.f, pd = 0.f;
                #pragma unroll
                for (int ni = 0; ni < 4; ni++) {
                    float v = acc[mi][ni][j];
                    ps += v * asv[ni];
                    pd += v * adv[ni];
                }
                #pragma unroll
                for (int o = 1; o < 16; o <<= 1) {
                    ps += __shfl_xor(ps, o, 64);
                    pd += __shfl_xor(pd, o, 64);
                }
                int grow = m0 + 64 * wr + 16 * mi + lk * 4 + j;
                if (lr == 0 && grow < nrows) {
                    a_src[grow * HH + wc] = ps;
                    a_dst[grow * HH + wc] = pd;
                }
            }
        }
    } else {  // NC == 64, single head; wave w owns rows [16w, 16w+16)
        f32x4 acc[4] = {};
        for (int k0 = 0; k0 < K; k0 += 32) {
            {
                int row = tid >> 2, ks = (tid & 3) * 8;
                int grow = m0 + row;
                short8 av = {};
                if (grow < nrows) av = *(const short8*)&((const u16*)Aptr)[(size_t)grow * K + k0 + ks];
                *(short8*)&As[row][ks] = av;
            }
            if (tid < 256) {
                int col = tid >> 2;
                int ks = (tid & 3) * 8;
                *(short8*)&Bs[col][ks] = *(const short8*)&Bt[(size_t)col * K + k0 + ks];
            }
            __syncthreads();
            short8 af = *(const short8*)&As[16 * w + lr][lk * 8];
            #pragma unroll
            for (int c = 0; c < 4; c++) {
                short8 bf = *(const short8*)&Bs[c * 16 + lr][lk * 8];
                acc[c] = __builtin_amdgcn_mfma_f32_16x16x32_bf16(af, bf, acc[c], 0, 0, 0);
            }
            __syncthreads();
        }
        #pragma unroll
        for (int c = 0; c < 4; c++) {
            #pragma unroll
            for (int j = 0; j < 4; j++) {
                int grow = m0 + 16 * w + lk * 4 + j;
                if (grow < nrows) Hb[(size_t)grow * NC + c * 16 + lr] = f2b(acc[c][j]);
            }
        }
        float asv[4], adv[4];
        #pragma unroll
        for (int c = 0; c < 4; c++) {
            asv[c] = as_[c * 16 + lr];
            adv[c] = ad_[c * 16 + lr];
        }
        #pragma unroll
        for (int j = 0; j < 4; j++) {
            float ps = 0.f, pd = 0.f;
            #pragma unroll
            for (int c = 0; c < 4; c++) {
                float v = acc[c][j];
                ps += v * asv[c];
                pd += v * adv[c];
            }
            #pragma unroll
            for (int o = 1; o < 16; o <<= 1) {
                ps += __shfl_xor(ps, o, 64);
                pd += __shfl_xor(pd, o, 64);
            }
            int grow = m0 + 16 * w + lk * 4 + j;
            if (lr == 0 && grow < nrows) {
                a_src[grow] = ps;
                a_dst[grow] = pd;
            }
        }
    }
}

// ---------------- global max of a_src per head (softmax shift bound)
template<int HH>
__global__ __launch_bounds__(256) void gmax_kernel(const float* __restrict__ a_src,
                                                   unsigned* __restrict__ gmaxu, int n_nodes) {
    float mx[HH];
    #pragma unroll
    for (int h = 0; h < HH; h++) mx[h] = -3.4e38f;
    for (int i = blockIdx.x * 256 + threadIdx.x; i < n_nodes; i += gridDim.x * 256) {
        #pragma unroll
        for (int h = 0; h < HH; h++) mx[h] = fmaxf(mx[h], a_src[i * HH + h]);
    }
    #pragma unroll
    for (int h = 0; h < HH; h++) {
        #pragma unroll
        for (int off = 32; off; off >>= 1) mx[h] = fmaxf(mx[h], __shfl_xor(mx[h], off, 64));
    }
    if ((threadIdx.x & 63) == 0) {
        #pragma unroll
        for (int h = 0; h < HH; h++) atomicMax(&gmaxu[h], fmono(mx[h]));
    }
}

// ---------------- CSR build: count / two-level scan / range-partitioned fill
__global__ void count_kernel(const int* __restrict__ ei, int* __restrict__ deg,
                             int E_, int n_nodes) {
    int e = blockIdx.x * 256 + threadIdx.x;
    int tot = E_ + n_nodes;
    if (e >= tot) return;
    int d = (e < E_) ? ei[E_ + e] : e - E_;
    atomicAdd(&deg[d], 1);
}

__global__ __launch_bounds__(256) void scan_reduce_kernel(const int* __restrict__ deg,
                                                          int* __restrict__ bsum, int n) {
    int i = blockIdx.x * 256 + threadIdx.x;
    int v = (i < n) ? deg[i] : 0;
    #pragma unroll
    for (int o = 32; o; o >>= 1) v += __shfl_xor(v, o, 64);
    __shared__ int ws[4];
    if ((threadIdx.x & 63) == 0) ws[threadIdx.x >> 6] = v;
    __syncthreads();
    if (threadIdx.x == 0) bsum[blockIdx.x] = ws[0] + ws[1] + ws[2] + ws[3];
}

// exclusive scan of nb (<=256) ints in place; also used for degree-histogram
__global__ __launch_bounds__(256) void scan_blocksums_kernel(int* __restrict__ bsum, int nb) {
    __shared__ int s[256];
    int t = threadIdx.x;
    int v = (t < nb) ? bsum[t] : 0;
    s[t] = v;
    __syncthreads();
    #pragma unroll
    for (int d = 1; d < 256; d <<= 1) {
        int x = (t >= d) ? s[t - d] : 0;
        __syncthreads();
        s[t] += x;
        __syncthreads();
    }
    if (t < nb) bsum[t] = s[t] - v;  // exclusive
}

__global__ __launch_bounds__(256) void scan_final_kernel(const int* __restrict__ deg,
                                                         const int* __restrict__ bsum,
                                                         int* __restrict__ off, int n) {
    __shared__ int s[256];
    int t = threadIdx.x;
    int i = blockIdx.x * 256 + t;
    int v = (i < n) ? deg[i] : 0;
    s[t] = v;
    __syncthreads();
    #pragma unroll
    for (int d = 1; d < 256; d <<= 1) {
        int x = (t >= d) ? s[t - d] : 0;
        __syncthreads();
        s[t] += x;
        __syncthreads();
    }
    int ex = s[t] - v + bsum[blockIdx.x];
    if (i < n) off[i] = ex;
    if (i == n - 1) off[n] = ex + v;
}

// fill restricted to dst range [d_lo, d_hi): active csr_src/cursor slice is
// ~1/4 of the buffer -> L2-resident writes instead of thrashing writebacks.
__global__ void fill_part_kernel(const int* __restrict__ ei, const int* __restrict__ off,
                                 int* __restrict__ cursor, int* __restrict__ csr_src,
                                 int E_, int n_nodes, int d_lo, int d_hi) {
    int e = blockIdx.x * 256 + threadIdx.x;
    int tot = E_ + n_nodes;
    if (e >= tot) return;
    int s, d;
    if (e < E_) { s = ei[e]; d = ei[E_ + e]; } else { s = d = e - E_; }
    if (d < d_lo || d >= d_hi) return;
    int pos = atomicAdd(&cursor[d], 1);
    csr_src[off[d] + pos] = s;
}

// ---------------- degree-sort permutation (descending degree -> blocks are
// degree-uniform AND heavy blocks dispatch first): histogram on reversed key,
// exclusive scan (reuse scan_blocksums), scatter.
__global__ void hist_kernel(const int* __restrict__ deg, int* __restrict__ hist, int n) {
    int i = blockIdx.x * 256 + threadIdx.x;
    if (i >= n) return;
    int b = 255 - min(deg[i], 255);
    atomicAdd(&hist[b], 1);
}

__global__ void scatter_kernel(const int* __restrict__ deg, const int* __restrict__ hoff,
                               int* __restrict__ hcur, int* __restrict__ perm, int n) {
    int i = blockIdx.x * 256 + threadIdx.x;
    if (i >= n) return;
    int b = 255 - min(deg[i], 255);
    int pos = atomicAdd(&hcur[b], 1);
    perm[hoff[b] + pos] = i;
}

// ---------------- fused GAT edge pass (big layers, HC=256): single walk,
// x4 unrolled gathers, alpha dedup via shuffle; degree-sorted node order.
__global__ __launch_bounds__(256) void gat_aggr_kernel(const int* __restrict__ perm,
                                                       const int* __restrict__ off,
                                                       const int* __restrict__ csr_src,
                                                       const u16* __restrict__ Hb,
                                                       const float* __restrict__ a_src,
                                                       const float* __restrict__ a_dst,
                                                       const unsigned* __restrict__ gmaxu,
                                                       const float* __restrict__ bias,
                                                       u16* __restrict__ outb16,
                                                       int n_nodes) {
    constexpr int HH = 4, HC = 256;
    int idx = blockIdx.x * 4 + (threadIdx.x >> 6);
    if (idx >= n_nodes) return;
    int d = perm[idx];
    int lane = threadIdx.x & 63;
    int hh = lane >> 4;            // head
    int g = lane & 15;             // index within head-group
    int gb = lane & 48;            // first lane of this head-group
    int o0 = off[d];
    int deg = off[d + 1] - o0;
    float adm = a_dst[d * HH + hh];
    float m = lrelu(funmono(gmaxu[hh]) + adm);

    float den = 0.f;
    float acc[4] = {};
    int j = 0;
    for (; j + 4 <= deg; j += 4) {
        int s0 = csr_src[o0 + j + 0];
        int s1 = csr_src[o0 + j + 1];
        int s2 = csr_src[o0 + j + 2];
        int s3 = csr_src[o0 + j + 3];
        int ssel = s3;
        if (g == 0) ssel = s0; else if (g == 1) ssel = s1; else if (g == 2) ssel = s2;
        float e = __expf(lrelu(a_src[ssel * HH + hh] + adm) - m);
        float e0 = __shfl(e, gb + 0, 64);
        float e1 = __shfl(e, gb + 1, 64);
        float e2 = __shfl(e, gb + 2, 64);
        float e3 = __shfl(e, gb + 3, 64);
        den += (e0 + e1) + (e2 + e3);
        uint2 h0 = *(const uint2*)&Hb[(size_t)s0 * HC + lane * 4];
        uint2 h1 = *(const uint2*)&Hb[(size_t)s1 * HC + lane * 4];
        uint2 h2 = *(const uint2*)&Hb[(size_t)s2 * HC + lane * 4];
        uint2 h3 = *(const uint2*)&Hb[(size_t)s3 * HC + lane * 4];
        acc[0] += e0 * __uint_as_float(h0.x << 16) + e1 * __uint_as_float(h1.x << 16)
                + e2 * __uint_as_float(h2.x << 16) + e3 * __uint_as_float(h3.x << 16);
        acc[1] += e0 * __uint_as_float(h0.x & 0xffff0000u) + e1 * __uint_as_float(h1.x & 0xffff0000u)
                + e2 * __uint_as_float(h2.x & 0xffff0000u) + e3 * __uint_as_float(h3.x & 0xffff0000u);
        acc[2] += e0 * __uint_as_float(h0.y << 16) + e1 * __uint_as_float(h1.y << 16)
                + e2 * __uint_as_float(h2.y << 16) + e3 * __uint_as_float(h3.y << 16);
        acc[3] += e0 * __uint_as_float(h0.y & 0xffff0000u) + e1 * __uint_as_float(h1.y & 0xffff0000u)
                + e2 * __uint_as_float(h2.y & 0xffff0000u) + e3 * __uint_as_float(h3.y & 0xffff0000u);
    }
    for (; j < deg; j++) {
        int s = csr_src[o0 + j];
        float al = __expf(lrelu(a_src[s * HH + hh] + adm) - m);
        den += al;
        uint2 hv = *(const uint2*)&Hb[(size_t)s * HC + lane * 4];
        acc[0] += al * __uint_as_float(hv.x << 16);
        acc[1] += al * __uint_as_float(hv.x & 0xffff0000u);
        acc[2] += al * __uint_as_float(hv.y << 16);
        acc[3] += al * __uint_as_float(hv.y & 0xffff0000u);
    }
    float inv = 1.f / (den + 1e-16f);
    float4 bv = *(const float4*)&bias[lane * 4];
    float v0 = fmaxf(acc[0] * inv + bv.x, 0.f);
    float v1 = fmaxf(acc[1] * inv + bv.y, 0.f);
    float v2 = fmaxf(acc[2] * inv + bv.z, 0.f);
    float v3 = fmaxf(acc[3] * inv + bv.w, 0.f);
    uint2 o;
    o.x = (unsigned)f2b(v0) | ((unsigned)f2b(v1) << 16);
    o.y = (unsigned)f2b(v2) | ((unsigned)f2b(v3) << 16);
    *(uint2*)&outb16[(size_t)d * HC + lane * 4] = o;
}

// ---------------- layer-3 GAT edge pass (HC=64, 1 head): 4 edges per wave
// instruction (16-lane group g = edge j+g), x2 unrolled (8 edges in flight),
// cross-group shfl_xor combine; degree-sorted node order.
__global__ __launch_bounds__(256) void gat_aggr3_kernel(const int* __restrict__ perm,
                                                        const int* __restrict__ off,
                                                        const int* __restrict__ csr_src,
                                                        const u16* __restrict__ Hb,
                                                        const float* __restrict__ a_src,
                                                        const float* __restrict__ a_dst,
                                                        const unsigned* __restrict__ gmaxu,
                                                        const float* __restrict__ bias,
                                                        float* __restrict__ outf32,
                                                        int n_nodes) {
    int idx = blockIdx.x * 4 + (threadIdx.x >> 6);
    if (idx >= n_nodes) return;
    int d = perm[idx];
    int lane = threadIdx.x & 63;
    int grp = lane >> 4;           // which edge of the 4
    int li = lane & 15;            // column quad within the row
    int o0 = off[d];
    int deg = off[d + 1] - o0;
    float adm = a_dst[d];
    float m = lrelu(funmono(gmaxu[0]) + adm);

    float den = 0.f;
    float a0 = 0.f, a1 = 0.f, a2 = 0.f, a3 = 0.f;
    int j = 0;
    for (; j + 8 <= deg; j += 8) {
        int sA = csr_src[o0 + j + grp];
        int sB = csr_src[o0 + j + 4 + grp];
        float alA = __expf(lrelu(a_src[sA] + adm) - m);
        float alB = __expf(lrelu(a_src[sB] + adm) - m);
        uint2 hA = *(const uint2*)&Hb[(size_t)sA * 64 + li * 4];
        uint2 hB = *(const uint2*)&Hb[(size_t)sB * 64 + li * 4];
        den += alA + alB;
        a0 += alA * __uint_as_float(hA.x << 16) + alB * __uint_as_float(hB.x << 16);
        a1 += alA * __uint_as_float(hA.x & 0xffff0000u) + alB * __uint_as_float(hB.x & 0xffff0000u);
        a2 += alA * __uint_as_float(hA.y << 16) + alB * __uint_as_float(hB.y << 16);
        a3 += alA * __uint_as_float(hA.y & 0xffff0000u) + alB * __uint_as_float(hB.y & 0xffff0000u);
    }
    for (; j < deg; j += 4) {
        int e = j + grp;
        float al = 0.f;
        unsigned hx = 0u, hy = 0u;
        if (e < deg) {
            int s = csr_src[o0 + e];
            al = __expf(lrelu(a_src[s] + adm) - m);
            uint2 hv = *(const uint2*)&Hb[(size_t)s * 64 + li * 4];
            hx = hv.x; hy = hv.y;
        }
        den += al;
        a0 += al * __uint_as_float(hx << 16);
        a1 += al * __uint_as_float(hx & 0xffff0000u);
        a2 += al * __uint_as_float(hy << 16);
        a3 += al * __uint_as_float(hy & 0xffff0000u);
    }
    // combine the 4 edge-groups (lanes with equal li share columns)
    #pragma unroll
    for (int o = 16; o < 64; o <<= 1) {
        den += __shfl_xor(den, o, 64);
        a0  += __shfl_xor(a0, o, 64);
        a1  += __shfl_xor(a1, o, 64);
        a2  += __shfl_xor(a2, o, 64);
        a3  += __shfl_xor(a3, o, 64);
    }
    if (grp == 0) {
        float inv = 1.f / (den + 1e-16f);
        float4 bv = *(const float4*)&bias[li * 4];
        float4 o;
        o.x = fmaxf(a0 * inv + bv.x, 0.f);
        o.y = fmaxf(a1 * inv + bv.y, 0.f);
        o.z = fmaxf(a2 * inv + bv.z, 0.f);
        o.w = fmaxf(a3 * inv + bv.w, 0.f);
        *(float4*)&outf32[(size_t)d * 64 + li * 4] = o;
    }
}

// ---------------- segment-sum pooling over sorted batch ids; lane = feature
__global__ __launch_bounds__(256) void pool_kernel(const float* __restrict__ H3,
                                                   const int* __restrict__ batch,
                                                   float* __restrict__ pooled, int n_nodes) {
    int wave = (blockIdx.x * 256 + threadIdx.x) >> 6;
    int lane = threadIdx.x & 63;
    int nwaves = gridDim.x * 4;
    int chunk = (n_nodes + nwaves - 1) / nwaves;
    int start = wave * chunk;
    int end = min(n_nodes, start + chunk);
    if (start >= end) return;
    int cur = batch[start];
    float acc = 0.f;
    for (int n = start; n < end; n++) {
        int g = batch[n];
        if (g != cur) { atomAddF(&pooled[cur * 64 + lane], acc); acc = 0.f; cur = g; }
        acc += H3[(size_t)n * 64 + lane];
    }
    atomAddF(&pooled[cur * 64 + lane], acc);
}

// ---------------- tiny MLP head
__global__ __launch_bounds__(64) void mlp_kernel(const float* __restrict__ pooled,
                                                 const float* __restrict__ Wm1,
                                                 const float* __restrict__ bm1,
                                                 const float* __restrict__ Wm2,
                                                 const float* __restrict__ bm2,
                                                 float* __restrict__ out) {
    __shared__ float sp[64], sh[64];
    int g = blockIdx.x, t = threadIdx.x;
    sp[t] = pooled[g * 64 + t];
    __syncthreads();
    float a = bm1[t];
    for (int k = 0; k < 64; k++) a += sp[k] * Wm1[k * 64 + t];
    sh[t] = a > 0.f ? a : 0.f;
    __syncthreads();
    if (t < 10) {
        float o = bm2[t];
        for (int j = 0; j < 64; j++) o += sh[j] * Wm2[j * 10 + t];
        out[g * 10 + t] = o;
    }
}

extern "C" void kernel_launch(void* const* d_in, const int* in_sizes, int n_in,
                              void* d_out, int out_size, void* d_ws, size_t ws_size,
                              hipStream_t stream) {
    const float* x   = (const float*)d_in[0];
    const int*   ei  = (const int*)d_in[1];
    const int*   bat = (const int*)d_in[2];
    const float* W1  = (const float*)d_in[3];
    const float* b1  = (const float*)d_in[4];
    const float* as1 = (const float*)d_in[5];
    const float* ad1 = (const float*)d_in[6];
    const float* W2  = (const float*)d_in[7];
    const float* b2  = (const float*)d_in[8];
    const float* as2 = (const float*)d_in[9];
    const float* ad2 = (const float*)d_in[10];
    const float* W3  = (const float*)d_in[11];
    const float* b3  = (const float*)d_in[12];
    const float* as3 = (const float*)d_in[13];
    const float* ad3 = (const float*)d_in[14];
    const float* Wm1 = (const float*)d_in[15];
    const float* bm1 = (const float*)d_in[16];
    const float* Wm2 = (const float*)d_in[17];
    const float* bm2 = (const float*)d_in[18];
    float* out = (float*)d_out;

    const int Nn = in_sizes[0] / F_IN;     // 50000
    const int Ee = in_sizes[1] / 2;        // 800000
    const int Et = Ee + Nn;

    // workspace layout
    char* wsp = (char*)d_ws;
    size_t off_b = 0;
    auto alloc = [&](size_t bytes) { void* p = wsp + off_b; off_b += (bytes + 255) & ~(size_t)255; return p; };
    u16*   HbA     = (u16*)alloc((size_t)Nn * 256 * 2);
    u16*   HbB     = (u16*)alloc((size_t)Nn * 256 * 2);
    float* Hf      = (float*)alloc((size_t)Nn * HID * 4);
    u16*   Wt1     = (u16*)alloc((size_t)256 * 128 * 2);
    u16*   Wt2     = (u16*)alloc((size_t)256 * 256 * 2);
    u16*   Wt3     = (u16*)alloc((size_t)64 * 256 * 2);
    float* a_src   = (float*)alloc((size_t)Nn * HEADS * 4);
    float* a_dst   = (float*)alloc((size_t)Nn * HEADS * 4);
    // one contiguous zeroed region:
    // gmaxu(16) + deg(Nn) + cursor(Nn) + pooled(64*64) + hist(256) + hcur(256)
    size_t zcount = 16 + (size_t)Nn * 2 + NGRP * HID + 512;
    unsigned* zbase = (unsigned*)alloc(zcount * 4);
    unsigned* gmaxu = zbase;                    // 3 layers: +0,+4,+8
    int*   deg     = (int*)(zbase + 16);
    int*   cursor  = deg + Nn;
    float* pooled  = (float*)(cursor + Nn);
    int*   hist    = (int*)(pooled + NGRP * HID);
    int*   hcur    = hist + 256;
    int*   bsum    = (int*)alloc((size_t)256 * 4);
    int*   csr_off = (int*)alloc((size_t)(Nn + 1) * 4);
    int*   csr_src = (int*)alloc((size_t)Et * 4);
    int*   perm    = (int*)alloc((size_t)Nn * 4);
    (void)ws_size;

    // ---- one-time weight conversion (single kernel)
    wtrans_all_kernel<<<(114688 + 255) / 256, 256, 0, stream>>>(W1, W2, W3, Wt1, Wt2, Wt3);

    // ---- zero gmaxu/deg/cursor/pooled/hist/hcur in one memset
    hipMemsetAsync(zbase, 0, zcount * 4, stream);

    // ---- CSR build (once, reused by all layers)
    int eb = (Et + 255) / 256;
    int nb = (Nn + 255) / 256;  // 196 <= 256
    count_kernel<<<eb, 256, 0, stream>>>(ei, deg, Ee, Nn);
    scan_reduce_kernel<<<nb, 256, 0, stream>>>(deg, bsum, Nn);
    scan_blocksums_kernel<<<1, 256, 0, stream>>>(bsum, nb);
    scan_final_kernel<<<nb, 256, 0, stream>>>(deg, bsum, csr_off, Nn);
    // range-partitioned fill: active csr_src/cursor slice stays L2-resident
    {
        int q = (Nn + 3) / 4;
        for (int p = 0; p < 4; p++) {
            int lo = p * q, hi = min(Nn, lo + q);
            fill_part_kernel<<<eb, 256, 0, stream>>>(ei, csr_off, cursor, csr_src,
                                                     Ee, Nn, lo, hi);
        }
    }
    // degree-sorted permutation (descending): uniform blocks, heavy blocks first
    hist_kernel<<<nb, 256, 0, stream>>>(deg, hist, Nn);
    scan_blocksums_kernel<<<1, 256, 0, stream>>>(hist, 256);
    scatter_kernel<<<nb, 256, 0, stream>>>(deg, hist, hcur, perm, Nn);

    const int gemm_blocks = (Nn + 127) / 128;
    const int nodeBlocks = (Nn + 3) / 4;

    // ---- layer 1 (fp32 x staged+converted in GEMM)
    gemm_att_kernel<128, 256, true><<<gemm_blocks, 512, 0, stream>>>(x, Wt1, as1, ad1,
                                                                     HbA, a_src, a_dst, Nn);
    gmax_kernel<4><<<64, 256, 0, stream>>>(a_src, gmaxu + 0, Nn);
    gat_aggr_kernel<<<nodeBlocks, 256, 0, stream>>>(perm, csr_off, csr_src, HbA,
                                                    a_src, a_dst, gmaxu + 0, b1, HbB, Nn);
    // ---- layer 2
    gemm_att_kernel<256, 256, false><<<gemm_blocks, 512, 0, stream>>>(HbB, Wt2, as2, ad2,
                                                                      HbA, a_src, a_dst, Nn);
    gmax_kernel<4><<<64, 256, 0, stream>>>(a_src, gmaxu + 4, Nn);
    gat_aggr_kernel<<<nodeBlocks, 256, 0, stream>>>(perm, csr_off, csr_src, HbA,
                                                    a_src, a_dst, gmaxu + 4, b2, HbB, Nn);
    // ---- layer 3 (heads=1, out fp32 for pooling)
    gemm_att_kernel<256, 64, false><<<gemm_blocks, 512, 0, stream>>>(HbB, Wt3, as3, ad3,
                                                                     HbA, a_src, a_dst, Nn);
    gmax_kernel<1><<<64, 256, 0, stream>>>(a_src, gmaxu + 8, Nn);
    gat_aggr3_kernel<<<nodeBlocks, 256, 0, stream>>>(perm, csr_off, csr_src, HbA,
                                                     a_src, a_dst, gmaxu + 8, b3, Hf, Nn);

    pool_kernel<<<128, 256, 0, stream>>>(Hf, bat, pooled, Nn);
    mlp_kernel<<<NGRP, 64, 0, stream>>>(pooled, Wm1, bm1, Wm2, bm2, out);
}

// Round 15
// 407.344 us; speedup vs baseline: 1.5810x; 1.5810x over previous
//
#include <hip/hip_runtime.h>
#include <hip/hip_bf16.h>

#define F_IN   128
#define HID    64
#define HEADS  4
#define OUTD   10
#define NGRP   64

typedef unsigned short u16;
typedef __attribute__((ext_vector_type(8))) short short8;
typedef __attribute__((ext_vector_type(4))) float f32x4;

__device__ __forceinline__ float atomAddF(float* p, float v) {
    return __hip_atomic_fetch_add(p, v, __ATOMIC_RELAXED, __HIP_MEMORY_SCOPE_AGENT);
}
__device__ __forceinline__ float lrelu(float f) { return f > 0.f ? f : 0.2f * f; }
__device__ __forceinline__ float b2f(u16 u) { return __uint_as_float(((unsigned)u) << 16); }
__device__ __forceinline__ u16 f2b(float f) {  // RNE
    unsigned u = __float_as_uint(f);
    return (u16)((u + 0x7fffu + ((u >> 16) & 1u)) >> 16);
}
__device__ __forceinline__ unsigned fmono(float f) {
    unsigned u = __float_as_uint(f);
    return (u & 0x80000000u) ? ~u : (u | 0x80000000u);
}
__device__ __forceinline__ float funmono(unsigned u) {
    return __uint_as_float((u & 0x80000000u) ? (u & 0x7FFFFFFFu) : ~u);
}

// ---------------- all three W[K][NC] fp32 -> Wt[NC][K] bf16, one kernel
__global__ __launch_bounds__(256) void wtrans_all_kernel(const float* __restrict__ W1,
                                                         const float* __restrict__ W2,
                                                         const float* __restrict__ W3,
                                                         u16* __restrict__ Wt1,
                                                         u16* __restrict__ Wt2,
                                                         u16* __restrict__ Wt3) {
    int i = blockIdx.x * 256 + threadIdx.x;
    if (i < 32768) {                       // W1: K=128, NC=256
        int n = i >> 7, k = i & 127;
        Wt1[i] = f2b(W1[(size_t)k * 256 + n]);
    } else if (i < 98304) {                // W2: K=256, NC=256
        int j = i - 32768;
        int n = j >> 8, k = j & 255;
        Wt2[j] = f2b(W2[(size_t)k * 256 + n]);
    } else if (i < 114688) {               // W3: K=256, NC=64
        int j = i - 98304;
        int n = j >> 8, k = j & 255;
        Wt3[j] = f2b(W3[(size_t)k * 64 + n]);   // W3 row stride is 64
    }
}

// ---------------- bf16 MFMA GEMM with fused attention-score epilogue.
// BM=128, 512 threads (8 waves).
template<int K, int NC, bool AF32>
__global__ __launch_bounds__(512) void gemm_att_kernel(const void* __restrict__ Aptr,
                                                       const u16* __restrict__ Bt,
                                                       const float* __restrict__ as_,
                                                       const float* __restrict__ ad_,
                                                       u16* __restrict__ Hb,
                                                       float* __restrict__ a_src,
                                                       float* __restrict__ a_dst,
                                                       int nrows) {
    constexpr int LDA = 40;  // bf16 elems/row incl pad: 80B stride, 16B aligned
    constexpr int HH = NC / 64;
    __shared__ u16 As[128][LDA];
    __shared__ u16 Bs[NC][LDA];
    int tid = threadIdx.x;
    int m0 = blockIdx.x * 128;
    int w = tid >> 6, l = tid & 63, lr = l & 15, lk = l >> 4;

    if constexpr (NC == 256) {
        int wr = w >> 2, wc = w & 3;   // row-group, col-group(=head)
        f32x4 acc[4][4] = {};
        for (int k0 = 0; k0 < K; k0 += 32) {
            {   // stage A tile 128x32: one short8 per thread
                int row = tid >> 2, ks = (tid & 3) * 8;
                int grow = m0 + row;
                short8 av = {};
                if (grow < nrows) {
                    if constexpr (AF32) {
                        const float* src = (const float*)Aptr + (size_t)grow * K + k0 + ks;
                        float4 v0 = *(const float4*)src;
                        float4 v1 = *(const float4*)(src + 4);
                        av[0] = (short)f2b(v0.x); av[1] = (short)f2b(v0.y);
                        av[2] = (short)f2b(v0.z); av[3] = (short)f2b(v0.w);
                        av[4] = (short)f2b(v1.x); av[5] = (short)f2b(v1.y);
                        av[6] = (short)f2b(v1.z); av[7] = (short)f2b(v1.w);
                    } else {
                        av = *(const short8*)&((const u16*)Aptr)[(size_t)grow * K + k0 + ks];
                    }
                }
                *(short8*)&As[row][ks] = av;
            }
            #pragma unroll
            for (int i = 0; i < 2; i++) {  // stage B tile 256x32: two short8 per thread
                int col = (tid >> 2) + 128 * i;
                int ks = (tid & 3) * 8;
                *(short8*)&Bs[col][ks] = *(const short8*)&Bt[(size_t)col * K + k0 + ks];
            }
            __syncthreads();
            short8 a[4], b[4];
            #pragma unroll
            for (int mi = 0; mi < 4; mi++) a[mi] = *(const short8*)&As[64 * wr + 16 * mi + lr][lk * 8];
            #pragma unroll
            for (int ni = 0; ni < 4; ni++) b[ni] = *(const short8*)&Bs[64 * wc + 16 * ni + lr][lk * 8];
            #pragma unroll
            for (int mi = 0; mi < 4; mi++)
                #pragma unroll
                for (int ni = 0; ni < 4; ni++)
                    acc[mi][ni] = __builtin_amdgcn_mfma_f32_16x16x32_bf16(a[mi], b[ni], acc[mi][ni], 0, 0, 0);
            __syncthreads();
        }
        // C write
        #pragma unroll
        for (int mi = 0; mi < 4; mi++) {
            #pragma unroll
            for (int j = 0; j < 4; j++) {
                int grow = m0 + 64 * wr + 16 * mi + lk * 4 + j;
                if (grow < nrows) {
                    #pragma unroll
                    for (int ni = 0; ni < 4; ni++)
                        Hb[(size_t)grow * NC + 64 * wc + 16 * ni + lr] = f2b(acc[mi][ni][j]);
                }
            }
        }
        // attention epilogue
        float asv[4], adv[4];
        #pragma unroll
        for (int ni = 0; ni < 4; ni++) {
            asv[ni] = as_[wc * 64 + 16 * ni + lr];
            adv[ni] = ad_[wc * 64 + 16 * ni + lr];
        }
        #pragma unroll
        for (int mi = 0; mi < 4; mi++) {
            #pragma unroll
            for (int j = 0; j < 4; j++) {
                float ps = 0.f, pd = 0.f;
                #pragma unroll
                for (int ni = 0; ni < 4; ni++) {
                    float v = acc[mi][ni][j];
                    ps += v * asv[ni];
                    pd += v * adv[ni];
                }
                #pragma unroll
                for (int o = 1; o < 16; o <<= 1) {
                    ps += __shfl_xor(ps, o, 64);
                    pd += __shfl_xor(pd, o, 64);
                }
                int grow = m0 + 64 * wr + 16 * mi + lk * 4 + j;
                if (lr == 0 && grow < nrows) {
                    a_src[grow * HH + wc] = ps;
                    a_dst[grow * HH + wc] = pd;
                }
            }
        }
    } else {  // NC == 64, single head; wave w owns rows [16w, 16w+16)
        f32x4 acc[4] = {};
        for (int k0 = 0; k0 < K; k0 += 32) {
            {
                int row = tid >> 2, ks = (tid & 3) * 8;
                int grow = m0 + row;
                short8 av = {};
                if (grow < nrows) av = *(const short8*)&((const u16*)Aptr)[(size_t)grow * K + k0 + ks];
                *(short8*)&As[row][ks] = av;
            }
            if (tid < 256) {
                int col = tid >> 2;
                int ks = (tid & 3) * 8;
                *(short8*)&Bs[col][ks] = *(const short8*)&Bt[(size_t)col * K + k0 + ks];
            }
            __syncthreads();
            short8 af = *(const short8*)&As[16 * w + lr][lk * 8];
            #pragma unroll
            for (int c = 0; c < 4; c++) {
                short8 bf = *(const short8*)&Bs[c * 16 + lr][lk * 8];
                acc[c] = __builtin_amdgcn_mfma_f32_16x16x32_bf16(af, bf, acc[c], 0, 0, 0);
            }
            __syncthreads();
        }
        #pragma unroll
        for (int c = 0; c < 4; c++) {
            #pragma unroll
            for (int j = 0; j < 4; j++) {
                int grow = m0 + 16 * w + lk * 4 + j;
                if (grow < nrows) Hb[(size_t)grow * NC + c * 16 + lr] = f2b(acc[c][j]);
            }
        }
        float asv[4], adv[4];
        #pragma unroll
        for (int c = 0; c < 4; c++) {
            asv[c] = as_[c * 16 + lr];
            adv[c] = ad_[c * 16 + lr];
        }
        #pragma unroll
        for (int j = 0; j < 4; j++) {
            float ps = 0.f, pd = 0.f;
            #pragma unroll
            for (int c = 0; c < 4; c++) {
                float v = acc[c][j];
                ps += v * asv[c];
                pd += v * adv[c];
            }
            #pragma unroll
            for (int o = 1; o < 16; o <<= 1) {
                ps += __shfl_xor(ps, o, 64);
                pd += __shfl_xor(pd, o, 64);
            }
            int grow = m0 + 16 * w + lk * 4 + j;
            if (lr == 0 && grow < nrows) {
                a_src[grow] = ps;
                a_dst[grow] = pd;
            }
        }
    }
}

// ---------------- global max of a_src per head (softmax shift bound)
template<int HH>
__global__ __launch_bounds__(256) void gmax_kernel(const float* __restrict__ a_src,
                                                   unsigned* __restrict__ gmaxu, int n_nodes) {
    float mx[HH];
    #pragma unroll
    for (int h = 0; h < HH; h++) mx[h] = -3.4e38f;
    for (int i = blockIdx.x * 256 + threadIdx.x; i < n_nodes; i += gridDim.x * 256) {
        #pragma unroll
        for (int h = 0; h < HH; h++) mx[h] = fmaxf(mx[h], a_src[i * HH + h]);
    }
    #pragma unroll
    for (int h = 0; h < HH; h++) {
        #pragma unroll
        for (int off = 32; off; off >>= 1) mx[h] = fmaxf(mx[h], __shfl_xor(mx[h], off, 64));
    }
    if ((threadIdx.x & 63) == 0) {
        #pragma unroll
        for (int h = 0; h < HH; h++) atomicMax(&gmaxu[h], fmono(mx[h]));
    }
}

// ---------------- CSR build: count / two-level scan / range-partitioned fill
__global__ void count_kernel(const int* __restrict__ ei, int* __restrict__ deg,
                             int E_, int n_nodes) {
    int e = blockIdx.x * 256 + threadIdx.x;
    int tot = E_ + n_nodes;
    if (e >= tot) return;
    int d = (e < E_) ? ei[E_ + e] : e - E_;
    atomicAdd(&deg[d], 1);
}

__global__ __launch_bounds__(256) void scan_reduce_kernel(const int* __restrict__ deg,
                                                          int* __restrict__ bsum, int n) {
    int i = blockIdx.x * 256 + threadIdx.x;
    int v = (i < n) ? deg[i] : 0;
    #pragma unroll
    for (int o = 32; o; o >>= 1) v += __shfl_xor(v, o, 64);
    __shared__ int ws[4];
    if ((threadIdx.x & 63) == 0) ws[threadIdx.x >> 6] = v;
    __syncthreads();
    if (threadIdx.x == 0) bsum[blockIdx.x] = ws[0] + ws[1] + ws[2] + ws[3];
}

// exclusive scan of nb (<=256) ints in place
__global__ __launch_bounds__(256) void scan_blocksums_kernel(int* __restrict__ bsum, int nb) {
    __shared__ int s[256];
    int t = threadIdx.x;
    int v = (t < nb) ? bsum[t] : 0;
    s[t] = v;
    __syncthreads();
    #pragma unroll
    for (int d = 1; d < 256; d <<= 1) {
        int x = (t >= d) ? s[t - d] : 0;
        __syncthreads();
        s[t] += x;
        __syncthreads();
    }
    if (t < nb) bsum[t] = s[t] - v;  // exclusive
}

__global__ __launch_bounds__(256) void scan_final_kernel(const int* __restrict__ deg,
                                                         const int* __restrict__ bsum,
                                                         int* __restrict__ off, int n) {
    __shared__ int s[256];
    int t = threadIdx.x;
    int i = blockIdx.x * 256 + t;
    int v = (i < n) ? deg[i] : 0;
    s[t] = v;
    __syncthreads();
    #pragma unroll
    for (int d = 1; d < 256; d <<= 1) {
        int x = (t >= d) ? s[t - d] : 0;
        __syncthreads();
        s[t] += x;
        __syncthreads();
    }
    int ex = s[t] - v + bsum[blockIdx.x];
    if (i < n) off[i] = ex;
    if (i == n - 1) off[n] = ex + v;
}

// fill restricted to dst range [d_lo, d_hi): L2-resident writes
__global__ void fill_part_kernel(const int* __restrict__ ei, const int* __restrict__ off,
                                 int* __restrict__ cursor, int* __restrict__ csr_src,
                                 int E_, int n_nodes, int d_lo, int d_hi) {
    int e = blockIdx.x * 256 + threadIdx.x;
    int tot = E_ + n_nodes;
    if (e >= tot) return;
    int s, d;
    if (e < E_) { s = ei[e]; d = ei[E_ + e]; } else { s = d = e - E_; }
    if (d < d_lo || d >= d_hi) return;
    int pos = atomicAdd(&cursor[d], 1);
    csr_src[off[d] + pos] = s;
}

// ---------------- degree-sort permutation, LDS-aggregated (avoid same-address
// global atomic convoy: deg is Poisson(17) -> ~20 hot buckets).
__global__ __launch_bounds__(256) void hist_kernel(const int* __restrict__ deg,
                                                   int* __restrict__ hist, int n) {
    __shared__ int lh[256];
    lh[threadIdx.x] = 0;
    __syncthreads();
    int i = blockIdx.x * 256 + threadIdx.x;
    if (i < n) {
        int b = 255 - min(deg[i], 255);
        atomicAdd(&lh[b], 1);
    }
    __syncthreads();
    int c = lh[threadIdx.x];
    if (c) atomicAdd(&hist[threadIdx.x], c);
}

__global__ __launch_bounds__(256) void scatter_kernel(const int* __restrict__ deg,
                                                      const int* __restrict__ hoff,
                                                      int* __restrict__ hcur,
                                                      int* __restrict__ perm, int n) {
    __shared__ int lh[256];
    __shared__ int lbase[256];
    lh[threadIdx.x] = 0;
    __syncthreads();
    int i = blockIdx.x * 256 + threadIdx.x;
    int b = 0, lpos = 0;
    if (i < n) {
        b = 255 - min(deg[i], 255);
        lpos = atomicAdd(&lh[b], 1);             // local rank within (block,bucket)
    }
    __syncthreads();
    int t = threadIdx.x;
    int c = lh[t];
    if (c) lbase[t] = atomicAdd(&hcur[t], c);    // one global RMW per (block,bucket)
    __syncthreads();
    if (i < n) perm[hoff[b] + lbase[b] + lpos] = i;
}

// ---------------- fused GAT edge pass (big layers, HC=256): single walk,
// x4 unrolled gathers, alpha dedup via shuffle; degree-sorted node order.
__global__ __launch_bounds__(256) void gat_aggr_kernel(const int* __restrict__ perm,
                                                       const int* __restrict__ off,
                                                       const int* __restrict__ csr_src,
                                                       const u16* __restrict__ Hb,
                                                       const float* __restrict__ a_src,
                                                       const float* __restrict__ a_dst,
                                                       const unsigned* __restrict__ gmaxu,
                                                       const float* __restrict__ bias,
                                                       u16* __restrict__ outb16,
                                                       int n_nodes) {
    constexpr int HH = 4, HC = 256;
    int idx = blockIdx.x * 4 + (threadIdx.x >> 6);
    if (idx >= n_nodes) return;
    int d = perm[idx];
    int lane = threadIdx.x & 63;
    int hh = lane >> 4;
    int g = lane & 15;
    int gb = lane & 48;
    int o0 = off[d];
    int deg = off[d + 1] - o0;
    float adm = a_dst[d * HH + hh];
    float m = lrelu(funmono(gmaxu[hh]) + adm);

    float den = 0.f;
    float acc[4] = {};
    int j = 0;
    for (; j + 4 <= deg; j += 4) {
        int s0 = csr_src[o0 + j + 0];
        int s1 = csr_src[o0 + j + 1];
        int s2 = csr_src[o0 + j + 2];
        int s3 = csr_src[o0 + j + 3];
        int ssel = s3;
        if (g == 0) ssel = s0; else if (g == 1) ssel = s1; else if (g == 2) ssel = s2;
        float e = __expf(lrelu(a_src[ssel * HH + hh] + adm) - m);
        float e0 = __shfl(e, gb + 0, 64);
        float e1 = __shfl(e, gb + 1, 64);
        float e2 = __shfl(e, gb + 2, 64);
        float e3 = __shfl(e, gb + 3, 64);
        den += (e0 + e1) + (e2 + e3);
        uint2 h0 = *(const uint2*)&Hb[(size_t)s0 * HC + lane * 4];
        uint2 h1 = *(const uint2*)&Hb[(size_t)s1 * HC + lane * 4];
        uint2 h2 = *(const uint2*)&Hb[(size_t)s2 * HC + lane * 4];
        uint2 h3 = *(const uint2*)&Hb[(size_t)s3 * HC + lane * 4];
        acc[0] += e0 * __uint_as_float(h0.x << 16) + e1 * __uint_as_float(h1.x << 16)
                + e2 * __uint_as_float(h2.x << 16) + e3 * __uint_as_float(h3.x << 16);
        acc[1] += e0 * __uint_as_float(h0.x & 0xffff0000u) + e1 * __uint_as_float(h1.x & 0xffff0000u)
                + e2 * __uint_as_float(h2.x & 0xffff0000u) + e3 * __uint_as_float(h3.x & 0xffff0000u);
        acc[2] += e0 * __uint_as_float(h0.y << 16) + e1 * __uint_as_float(h1.y << 16)
                + e2 * __uint_as_float(h2.y << 16) + e3 * __uint_as_float(h3.y << 16);
        acc[3] += e0 * __uint_as_float(h0.y & 0xffff0000u) + e1 * __uint_as_float(h1.y & 0xffff0000u)
                + e2 * __uint_as_float(h2.y & 0xffff0000u) + e3 * __uint_as_float(h3.y & 0xffff0000u);
    }
    for (; j < deg; j++) {
        int s = csr_src[o0 + j];
        float al = __expf(lrelu(a_src[s * HH + hh] + adm) - m);
        den += al;
        uint2 hv = *(const uint2*)&Hb[(size_t)s * HC + lane * 4];
        acc[0] += al * __uint_as_float(hv.x << 16);
        acc[1] += al * __uint_as_float(hv.x & 0xffff0000u);
        acc[2] += al * __uint_as_float(hv.y << 16);
        acc[3] += al * __uint_as_float(hv.y & 0xffff0000u);
    }
    float inv = 1.f / (den + 1e-16f);
    float4 bv = *(const float4*)&bias[lane * 4];
    float v0 = fmaxf(acc[0] * inv + bv.x, 0.f);
    float v1 = fmaxf(acc[1] * inv + bv.y, 0.f);
    float v2 = fmaxf(acc[2] * inv + bv.z, 0.f);
    float v3 = fmaxf(acc[3] * inv + bv.w, 0.f);
    uint2 o;
    o.x = (unsigned)f2b(v0) | ((unsigned)f2b(v1) << 16);
    o.y = (unsigned)f2b(v2) | ((unsigned)f2b(v3) << 16);
    *(uint2*)&outb16[(size_t)d * HC + lane * 4] = o;
}

// ---------------- layer-3 GAT edge pass (HC=64, 1 head): 4 edges per wave
// instruction, x2 unrolled, cross-group shfl_xor combine; degree-sorted.
__global__ __launch_bounds__(256) void gat_aggr3_kernel(const int* __restrict__ perm,
                                                        const int* __restrict__ off,
                                                        const int* __restrict__ csr_src,
                                                        const u16* __restrict__ Hb,
                                                        const float* __restrict__ a_src,
                                                        const float* __restrict__ a_dst,
                                                        const unsigned* __restrict__ gmaxu,
                                                        const float* __restrict__ bias,
                                                        float* __restrict__ outf32,
                                                        int n_nodes) {
    int idx = blockIdx.x * 4 + (threadIdx.x >> 6);
    if (idx >= n_nodes) return;
    int d = perm[idx];
    int lane = threadIdx.x & 63;
    int grp = lane >> 4;
    int li = lane & 15;
    int o0 = off[d];
    int deg = off[d + 1] - o0;
    float adm = a_dst[d];
    float m = lrelu(funmono(gmaxu[0]) + adm);

    float den = 0.f;
    float a0 = 0.f, a1 = 0.f, a2 = 0.f, a3 = 0.f;
    int j = 0;
    for (; j + 8 <= deg; j += 8) {
        int sA = csr_src[o0 + j + grp];
        int sB = csr_src[o0 + j + 4 + grp];
        float alA = __expf(lrelu(a_src[sA] + adm) - m);
        float alB = __expf(lrelu(a_src[sB] + adm) - m);
        uint2 hA = *(const uint2*)&Hb[(size_t)sA * 64 + li * 4];
        uint2 hB = *(const uint2*)&Hb[(size_t)sB * 64 + li * 4];
        den += alA + alB;
        a0 += alA * __uint_as_float(hA.x << 16) + alB * __uint_as_float(hB.x << 16);
        a1 += alA * __uint_as_float(hA.x & 0xffff0000u) + alB * __uint_as_float(hB.x & 0xffff0000u);
        a2 += alA * __uint_as_float(hA.y << 16) + alB * __uint_as_float(hB.y << 16);
        a3 += alA * __uint_as_float(hA.y & 0xffff0000u) + alB * __uint_as_float(hB.y & 0xffff0000u);
    }
    for (; j < deg; j += 4) {
        int e = j + grp;
        float al = 0.f;
        unsigned hx = 0u, hy = 0u;
        if (e < deg) {
            int s = csr_src[o0 + e];
            al = __expf(lrelu(a_src[s] + adm) - m);
            uint2 hv = *(const uint2*)&Hb[(size_t)s * 64 + li * 4];
            hx = hv.x; hy = hv.y;
        }
        den += al;
        a0 += al * __uint_as_float(hx << 16);
        a1 += al * __uint_as_float(hx & 0xffff0000u);
        a2 += al * __uint_as_float(hy << 16);
        a3 += al * __uint_as_float(hy & 0xffff0000u);
    }
    #pragma unroll
    for (int o = 16; o < 64; o <<= 1) {
        den += __shfl_xor(den, o, 64);
        a0  += __shfl_xor(a0, o, 64);
        a1  += __shfl_xor(a1, o, 64);
        a2  += __shfl_xor(a2, o, 64);
        a3  += __shfl_xor(a3, o, 64);
    }
    if (grp == 0) {
        float inv = 1.f / (den + 1e-16f);
        float4 bv = *(const float4*)&bias[li * 4];
        float4 o;
        o.x = fmaxf(a0 * inv + bv.x, 0.f);
        o.y = fmaxf(a1 * inv + bv.y, 0.f);
        o.z = fmaxf(a2 * inv + bv.z, 0.f);
        o.w = fmaxf(a3 * inv + bv.w, 0.f);
        *(float4*)&outf32[(size_t)d * 64 + li * 4] = o;
    }
}

// ---------------- segment-sum pooling over sorted batch ids; lane = feature
__global__ __launch_bounds__(256) void pool_kernel(const float* __restrict__ H3,
                                                   const int* __restrict__ batch,
                                                   float* __restrict__ pooled, int n_nodes) {
    int wave = (blockIdx.x * 256 + threadIdx.x) >> 6;
    int lane = threadIdx.x & 63;
    int nwaves = gridDim.x * 4;
    int chunk = (n_nodes + nwaves - 1) / nwaves;
    int start = wave * chunk;
    int end = min(n_nodes, start + chunk);
    if (start >= end) return;
    int cur = batch[start];
    float acc = 0.f;
    for (int n = start; n < end; n++) {
        int g = batch[n];
        if (g != cur) { atomAddF(&pooled[cur * 64 + lane], acc); acc = 0.f; cur = g; }
        acc += H3[(size_t)n * 64 + lane];
    }
    atomAddF(&pooled[cur * 64 + lane], acc);
}

// ---------------- tiny MLP head
__global__ __launch_bounds__(64) void mlp_kernel(const float* __restrict__ pooled,
                                                 const float* __restrict__ Wm1,
                                                 const float* __restrict__ bm1,
                                                 const float* __restrict__ Wm2,
                                                 const float* __restrict__ bm2,
                                                 float* __restrict__ out) {
    __shared__ float sp[64], sh[64];
    int g = blockIdx.x, t = threadIdx.x;
    sp[t] = pooled[g * 64 + t];
    __syncthreads();
    float a = bm1[t];
    for (int k = 0; k < 64; k++) a += sp[k] * Wm1[k * 64 + t];
    sh[t] = a > 0.f ? a : 0.f;
    __syncthreads();
    if (t < 10) {
        float o = bm2[t];
        for (int j = 0; j < 64; j++) o += sh[j] * Wm2[j * 10 + t];
        out[g * 10 + t] = o;
    }
}

extern "C" void kernel_launch(void* const* d_in, const int* in_sizes, int n_in,
                              void* d_out, int out_size, void* d_ws, size_t ws_size,
                              hipStream_t stream) {
    const float* x   = (const float*)d_in[0];
    const int*   ei  = (const int*)d_in[1];
    const int*   bat = (const int*)d_in[2];
    const float* W1  = (const float*)d_in[3];
    const float* b1  = (const float*)d_in[4];
    const float* as1 = (const float*)d_in[5];
    const float* ad1 = (const float*)d_in[6];
    const float* W2  = (const float*)d_in[7];
    const float* b2  = (const float*)d_in[8];
    const float* as2 = (const float*)d_in[9];
    const float* ad2 = (const float*)d_in[10];
    const float* W3  = (const float*)d_in[11];
    const float* b3  = (const float*)d_in[12];
    const float* as3 = (const float*)d_in[13];
    const float* ad3 = (const float*)d_in[14];
    const float* Wm1 = (const float*)d_in[15];
    const float* bm1 = (const float*)d_in[16];
    const float* Wm2 = (const float*)d_in[17];
    const float* bm2 = (const float*)d_in[18];
    float* out = (float*)d_out;

    const int Nn = in_sizes[0] / F_IN;     // 50000
    const int Ee = in_sizes[1] / 2;        // 800000
    const int Et = Ee + Nn;

    // workspace layout
    char* wsp = (char*)d_ws;
    size_t off_b = 0;
    auto alloc = [&](size_t bytes) { void* p = wsp + off_b; off_b += (bytes + 255) & ~(size_t)255; return p; };
    u16*   HbA     = (u16*)alloc((size_t)Nn * 256 * 2);
    u16*   HbB     = (u16*)alloc((size_t)Nn * 256 * 2);
    float* Hf      = (float*)alloc((size_t)Nn * HID * 4);
    u16*   Wt1     = (u16*)alloc((size_t)256 * 128 * 2);
    u16*   Wt2     = (u16*)alloc((size_t)256 * 256 * 2);
    u16*   Wt3     = (u16*)alloc((size_t)64 * 256 * 2);
    float* a_src   = (float*)alloc((size_t)Nn * HEADS * 4);
    float* a_dst   = (float*)alloc((size_t)Nn * HEADS * 4);
    // one contiguous zeroed region:
    // gmaxu(16) + deg(Nn) + cursor(Nn) + pooled(64*64) + hist(256) + hcur(256)
    size_t zcount = 16 + (size_t)Nn * 2 + NGRP * HID + 512;
    unsigned* zbase = (unsigned*)alloc(zcount * 4);
    unsigned* gmaxu = zbase;                    // 3 layers: +0,+4,+8
    int*   deg     = (int*)(zbase + 16);
    int*   cursor  = deg + Nn;
    float* pooled  = (float*)(cursor + Nn);
    int*   hist    = (int*)(pooled + NGRP * HID);
    int*   hcur    = hist + 256;
    int*   bsum    = (int*)alloc((size_t)256 * 4);
    int*   csr_off = (int*)alloc((size_t)(Nn + 1) * 4);
    int*   csr_src = (int*)alloc((size_t)Et * 4);
    int*   perm    = (int*)alloc((size_t)Nn * 4);
    (void)ws_size;

    // ---- one-time weight conversion (single kernel)
    wtrans_all_kernel<<<(114688 + 255) / 256, 256, 0, stream>>>(W1, W2, W3, Wt1, Wt2, Wt3);

    // ---- zero gmaxu/deg/cursor/pooled/hist/hcur in one memset
    hipMemsetAsync(zbase, 0, zcount * 4, stream);

    // ---- CSR build (once, reused by all layers)
    int eb = (Et + 255) / 256;
    int nb = (Nn + 255) / 256;  // 196 <= 256
    count_kernel<<<eb, 256, 0, stream>>>(ei, deg, Ee, Nn);
    scan_reduce_kernel<<<nb, 256, 0, stream>>>(deg, bsum, Nn);
    scan_blocksums_kernel<<<1, 256, 0, stream>>>(bsum, nb);
    scan_final_kernel<<<nb, 256, 0, stream>>>(deg, bsum, csr_off, Nn);
    // range-partitioned fill: active csr_src/cursor slice stays L2-resident
    {
        int q = (Nn + 3) / 4;
        for (int p = 0; p < 4; p++) {
            int lo = p * q, hi = min(Nn, lo + q);
            fill_part_kernel<<<eb, 256, 0, stream>>>(ei, csr_off, cursor, csr_src,
                                                     Ee, Nn, lo, hi);
        }
    }
    // degree-sorted permutation (descending), LDS-aggregated build
    hist_kernel<<<nb, 256, 0, stream>>>(deg, hist, Nn);
    scan_blocksums_kernel<<<1, 256, 0, stream>>>(hist, 256);
    scatter_kernel<<<nb, 256, 0, stream>>>(deg, hist, hcur, perm, Nn);

    const int gemm_blocks = (Nn + 127) / 128;
    const int nodeBlocks = (Nn + 3) / 4;

    // ---- layer 1 (fp32 x staged+converted in GEMM)
    gemm_att_kernel<128, 256, true><<<gemm_blocks, 512, 0, stream>>>(x, Wt1, as1, ad1,
                                                                     HbA, a_src, a_dst, Nn);
    gmax_kernel<4><<<64, 256, 0, stream>>>(a_src, gmaxu + 0, Nn);
    gat_aggr_kernel<<<nodeBlocks, 256, 0, stream>>>(perm, csr_off, csr_src, HbA,
                                                    a_src, a_dst, gmaxu + 0, b1, HbB, Nn);
    // ---- layer 2
    gemm_att_kernel<256, 256, false><<<gemm_blocks, 512, 0, stream>>>(HbB, Wt2, as2, ad2,
                                                                      HbA, a_src, a_dst, Nn);
    gmax_kernel<4><<<64, 256, 0, stream>>>(a_src, gmaxu + 4, Nn);
    gat_aggr_kernel<<<nodeBlocks, 256, 0, stream>>>(perm, csr_off, csr_src, HbA,
                                                    a_src, a_dst, gmaxu + 4, b2, HbB, Nn);
    // ---- layer 3 (heads=1, out fp32 for pooling)
    gemm_att_kernel<256, 64, false><<<gemm_blocks, 512, 0, stream>>>(HbB, Wt3, as3, ad3,
                                                                     HbA, a_src, a_dst, Nn);
    gmax_kernel<1><<<64, 256, 0, stream>>>(a_src, gmaxu + 8, Nn);
    gat_aggr3_kernel<<<nodeBlocks, 256, 0, stream>>>(perm, csr_off, csr_src, HbA,
                                                     a_src, a_dst, gmaxu + 8, b3, Hf, Nn);

    pool_kernel<<<128, 256, 0, stream>>>(Hf, bat, pooled, Nn);
    mlp_kernel<<<NGRP, 64, 0, stream>>>(pooled, Wm1, bm1, Wm2, bm2, out);
}

// Round 16
// 389.792 us; speedup vs baseline: 1.6522x; 1.0450x over previous
//
#include <hip/hip_runtime.h>
#include <hip/hip_bf16.h>

#define F_IN   128
#define HID    64
#define HEADS  4
#define OUTD   10
#define NGRP   64

typedef unsigned short u16;
typedef __attribute__((ext_vector_type(8))) short short8;
typedef __attribute__((ext_vector_type(4))) float f32x4;

__device__ __forceinline__ float atomAddF(float* p, float v) {
    return __hip_atomic_fetch_add(p, v, __ATOMIC_RELAXED, __HIP_MEMORY_SCOPE_AGENT);
}
__device__ __forceinline__ float lrelu(float f) { return f > 0.f ? f : 0.2f * f; }
__device__ __forceinline__ float b2f(u16 u) { return __uint_as_float(((unsigned)u) << 16); }
__device__ __forceinline__ u16 f2b(float f) {  // RNE
    unsigned u = __float_as_uint(f);
    return (u16)((u + 0x7fffu + ((u >> 16) & 1u)) >> 16);
}
__device__ __forceinline__ unsigned fmono(float f) {
    unsigned u = __float_as_uint(f);
    return (u & 0x80000000u) ? ~u : (u | 0x80000000u);
}
__device__ __forceinline__ float funmono(unsigned u) {
    return __uint_as_float((u & 0x80000000u) ? (u & 0x7FFFFFFFu) : ~u);
}

// ---------------- all three W[K][NC] fp32 -> Wt[NC][K] bf16, one kernel
__global__ __launch_bounds__(256) void wtrans_all_kernel(const float* __restrict__ W1,
                                                         const float* __restrict__ W2,
                                                         const float* __restrict__ W3,
                                                         u16* __restrict__ Wt1,
                                                         u16* __restrict__ Wt2,
                                                         u16* __restrict__ Wt3) {
    int i = blockIdx.x * 256 + threadIdx.x;
    if (i < 32768) {                       // W1: K=128, NC=256
        int n = i >> 7, k = i & 127;
        Wt1[i] = f2b(W1[(size_t)k * 256 + n]);
    } else if (i < 98304) {                // W2: K=256, NC=256
        int j = i - 32768;
        int n = j >> 8, k = j & 255;
        Wt2[j] = f2b(W2[(size_t)k * 256 + n]);
    } else if (i < 114688) {               // W3: K=256, NC=64
        int j = i - 98304;
        int n = j >> 8, k = j & 255;
        Wt3[j] = f2b(W3[(size_t)k * 64 + n]);   // W3 row stride is 64
    }
}

// ---------------- bf16 MFMA GEMM with fused attention-score epilogue.
// BM=128, 512 threads (8 waves).
template<int K, int NC, bool AF32>
__global__ __launch_bounds__(512) void gemm_att_kernel(const void* __restrict__ Aptr,
                                                       const u16* __restrict__ Bt,
                                                       const float* __restrict__ as_,
                                                       const float* __restrict__ ad_,
                                                       u16* __restrict__ Hb,
                                                       float* __restrict__ a_src,
                                                       float* __restrict__ a_dst,
                                                       int nrows) {
    constexpr int LDA = 40;  // bf16 elems/row incl pad: 80B stride, 16B aligned
    constexpr int HH = NC / 64;
    __shared__ u16 As[128][LDA];
    __shared__ u16 Bs[NC][LDA];
    int tid = threadIdx.x;
    int m0 = blockIdx.x * 128;
    int w = tid >> 6, l = tid & 63, lr = l & 15, lk = l >> 4;

    if constexpr (NC == 256) {
        int wr = w >> 2, wc = w & 3;   // row-group, col-group(=head)
        f32x4 acc[4][4] = {};
        for (int k0 = 0; k0 < K; k0 += 32) {
            {   // stage A tile 128x32: one short8 per thread
                int row = tid >> 2, ks = (tid & 3) * 8;
                int grow = m0 + row;
                short8 av = {};
                if (grow < nrows) {
                    if constexpr (AF32) {
                        const float* src = (const float*)Aptr + (size_t)grow * K + k0 + ks;
                        float4 v0 = *(const float4*)src;
                        float4 v1 = *(const float4*)(src + 4);
                        av[0] = (short)f2b(v0.x); av[1] = (short)f2b(v0.y);
                        av[2] = (short)f2b(v0.z); av[3] = (short)f2b(v0.w);
                        av[4] = (short)f2b(v1.x); av[5] = (short)f2b(v1.y);
                        av[6] = (short)f2b(v1.z); av[7] = (short)f2b(v1.w);
                    } else {
                        av = *(const short8*)&((const u16*)Aptr)[(size_t)grow * K + k0 + ks];
                    }
                }
                *(short8*)&As[row][ks] = av;
            }
            #pragma unroll
            for (int i = 0; i < 2; i++) {  // stage B tile 256x32: two short8 per thread
                int col = (tid >> 2) + 128 * i;
                int ks = (tid & 3) * 8;
                *(short8*)&Bs[col][ks] = *(const short8*)&Bt[(size_t)col * K + k0 + ks];
            }
            __syncthreads();
            short8 a[4], b[4];
            #pragma unroll
            for (int mi = 0; mi < 4; mi++) a[mi] = *(const short8*)&As[64 * wr + 16 * mi + lr][lk * 8];
            #pragma unroll
            for (int ni = 0; ni < 4; ni++) b[ni] = *(const short8*)&Bs[64 * wc + 16 * ni + lr][lk * 8];
            #pragma unroll
            for (int mi = 0; mi < 4; mi++)
                #pragma unroll
                for (int ni = 0; ni < 4; ni++)
                    acc[mi][ni] = __builtin_amdgcn_mfma_f32_16x16x32_bf16(a[mi], b[ni], acc[mi][ni], 0, 0, 0);
            __syncthreads();
        }
        // C write
        #pragma unroll
        for (int mi = 0; mi < 4; mi++) {
            #pragma unroll
            for (int j = 0; j < 4; j++) {
                int grow = m0 + 64 * wr + 16 * mi + lk * 4 + j;
                if (grow < nrows) {
                    #pragma unroll
                    for (int ni = 0; ni < 4; ni++)
                        Hb[(size_t)grow * NC + 64 * wc + 16 * ni + lr] = f2b(acc[mi][ni][j]);
                }
            }
        }
        // attention epilogue
        float asv[4], adv[4];
        #pragma unroll
        for (int ni = 0; ni < 4; ni++) {
            asv[ni] = as_[wc * 64 + 16 * ni + lr];
            adv[ni] = ad_[wc * 64 + 16 * ni + lr];
        }
        #pragma unroll
        for (int mi = 0; mi < 4; mi++) {
            #pragma unroll
            for (int j = 0; j < 4; j++) {
                float ps = 0.f, pd = 0.f;
                #pragma unroll
                for (int ni = 0; ni < 4; ni++) {
                    float v = acc[mi][ni][j];
                    ps += v * asv[ni];
                    pd += v * adv[ni];
                }
                #pragma unroll
                for (int o = 1; o < 16; o <<= 1) {
                    ps += __shfl_xor(ps, o, 64);
                    pd += __shfl_xor(pd, o, 64);
                }
                int grow = m0 + 64 * wr + 16 * mi + lk * 4 + j;
                if (lr == 0 && grow < nrows) {
                    a_src[grow * HH + wc] = ps;
                    a_dst[grow * HH + wc] = pd;
                }
            }
        }
    } else {  // NC == 64, single head; wave w owns rows [16w, 16w+16)
        f32x4 acc[4] = {};
        for (int k0 = 0; k0 < K; k0 += 32) {
            {
                int row = tid >> 2, ks = (tid & 3) * 8;
                int grow = m0 + row;
                short8 av = {};
                if (grow < nrows) av = *(const short8*)&((const u16*)Aptr)[(size_t)grow * K + k0 + ks];
                *(short8*)&As[row][ks] = av;
            }
            if (tid < 256) {
                int col = tid >> 2;
                int ks = (tid & 3) * 8;
                *(short8*)&Bs[col][ks] = *(const short8*)&Bt[(size_t)col * K + k0 + ks];
            }
            __syncthreads();
            short8 af = *(const short8*)&As[16 * w + lr][lk * 8];
            #pragma unroll
            for (int c = 0; c < 4; c++) {
                short8 bf = *(const short8*)&Bs[c * 16 + lr][lk * 8];
                acc[c] = __builtin_amdgcn_mfma_f32_16x16x32_bf16(af, bf, acc[c], 0, 0, 0);
            }
            __syncthreads();
        }
        #pragma unroll
        for (int c = 0; c < 4; c++) {
            #pragma unroll
            for (int j = 0; j < 4; j++) {
                int grow = m0 + 16 * w + lk * 4 + j;
                if (grow < nrows) Hb[(size_t)grow * NC + c * 16 + lr] = f2b(acc[c][j]);
            }
        }
        float asv[4], adv[4];
        #pragma unroll
        for (int c = 0; c < 4; c++) {
            asv[c] = as_[c * 16 + lr];
            adv[c] = ad_[c * 16 + lr];
        }
        #pragma unroll
        for (int j = 0; j < 4; j++) {
            float ps = 0.f, pd = 0.f;
            #pragma unroll
            for (int c = 0; c < 4; c++) {
                float v = acc[c][j];
                ps += v * asv[c];
                pd += v * adv[c];
            }
            #pragma unroll
            for (int o = 1; o < 16; o <<= 1) {
                ps += __shfl_xor(ps, o, 64);
                pd += __shfl_xor(pd, o, 64);
            }
            int grow = m0 + 16 * w + lk * 4 + j;
            if (lr == 0 && grow < nrows) {
                a_src[grow] = ps;
                a_dst[grow] = pd;
            }
        }
    }
}

// ---------------- global max of a_src per head (softmax shift bound)
template<int HH>
__global__ __launch_bounds__(256) void gmax_kernel(const float* __restrict__ a_src,
                                                   unsigned* __restrict__ gmaxu, int n_nodes) {
    float mx[HH];
    #pragma unroll
    for (int h = 0; h < HH; h++) mx[h] = -3.4e38f;
    for (int i = blockIdx.x * 256 + threadIdx.x; i < n_nodes; i += gridDim.x * 256) {
        #pragma unroll
        for (int h = 0; h < HH; h++) mx[h] = fmaxf(mx[h], a_src[i * HH + h]);
    }
    #pragma unroll
    for (int h = 0; h < HH; h++) {
        #pragma unroll
        for (int off = 32; off; off >>= 1) mx[h] = fmaxf(mx[h], __shfl_xor(mx[h], off, 64));
    }
    if ((threadIdx.x & 63) == 0) {
        #pragma unroll
        for (int h = 0; h < HH; h++) atomicMax(&gmaxu[h], fmono(mx[h]));
    }
}

// ---------------- CSR build: count / two-level scan / range-partitioned fill
__global__ void count_kernel(const int* __restrict__ ei, int* __restrict__ deg,
                             int E_, int n_nodes) {
    int e = blockIdx.x * 256 + threadIdx.x;
    int tot = E_ + n_nodes;
    if (e >= tot) return;
    int d = (e < E_) ? ei[E_ + e] : e - E_;
    atomicAdd(&deg[d], 1);
}

__global__ __launch_bounds__(256) void scan_reduce_kernel(const int* __restrict__ deg,
                                                          int* __restrict__ bsum, int n) {
    int i = blockIdx.x * 256 + threadIdx.x;
    int v = (i < n) ? deg[i] : 0;
    #pragma unroll
    for (int o = 32; o; o >>= 1) v += __shfl_xor(v, o, 64);
    __shared__ int ws[4];
    if ((threadIdx.x & 63) == 0) ws[threadIdx.x >> 6] = v;
    __syncthreads();
    if (threadIdx.x == 0) bsum[blockIdx.x] = ws[0] + ws[1] + ws[2] + ws[3];
}

// exclusive scan of nb (<=256) ints in place
__global__ __launch_bounds__(256) void scan_blocksums_kernel(int* __restrict__ bsum, int nb) {
    __shared__ int s[256];
    int t = threadIdx.x;
    int v = (t < nb) ? bsum[t] : 0;
    s[t] = v;
    __syncthreads();
    #pragma unroll
    for (int d = 1; d < 256; d <<= 1) {
        int x = (t >= d) ? s[t - d] : 0;
        __syncthreads();
        s[t] += x;
        __syncthreads();
    }
    if (t < nb) bsum[t] = s[t] - v;  // exclusive
}

__global__ __launch_bounds__(256) void scan_final_kernel(const int* __restrict__ deg,
                                                         const int* __restrict__ bsum,
                                                         int* __restrict__ off, int n) {
    __shared__ int s[256];
    int t = threadIdx.x;
    int i = blockIdx.x * 256 + t;
    int v = (i < n) ? deg[i] : 0;
    s[t] = v;
    __syncthreads();
    #pragma unroll
    for (int d = 1; d < 256; d <<= 1) {
        int x = (t >= d) ? s[t - d] : 0;
        __syncthreads();
        s[t] += x;
        __syncthreads();
    }
    int ex = s[t] - v + bsum[blockIdx.x];
    if (i < n) off[i] = ex;
    if (i == n - 1) off[n] = ex + v;
}

// fill restricted to dst range [d_lo, d_hi): L2-resident writes
__global__ void fill_part_kernel(const int* __restrict__ ei, const int* __restrict__ off,
                                 int* __restrict__ cursor, int* __restrict__ csr_src,
                                 int E_, int n_nodes, int d_lo, int d_hi) {
    int e = blockIdx.x * 256 + threadIdx.x;
    int tot = E_ + n_nodes;
    if (e >= tot) return;
    int s, d;
    if (e < E_) { s = ei[e]; d = ei[E_ + e]; } else { s = d = e - E_; }
    if (d < d_lo || d >= d_hi) return;
    int pos = atomicAdd(&cursor[d], 1);
    csr_src[off[d] + pos] = s;
}

// ---------------- fused GAT edge pass (big layers, HC=256): single walk,
// x4 unrolled gathers, alpha dedup via shuffle.
__global__ __launch_bounds__(256) void gat_aggr_kernel(const int* __restrict__ off,
                                                       const int* __restrict__ csr_src,
                                                       const u16* __restrict__ Hb,
                                                       const float* __restrict__ a_src,
                                                       const float* __restrict__ a_dst,
                                                       const unsigned* __restrict__ gmaxu,
                                                       const float* __restrict__ bias,
                                                       u16* __restrict__ outb16,
                                                       int n_nodes) {
    constexpr int HH = 4, HC = 256;
    int d = blockIdx.x * 4 + (threadIdx.x >> 6);
    if (d >= n_nodes) return;
    int lane = threadIdx.x & 63;
    int hh = lane >> 4;
    int g = lane & 15;
    int gb = lane & 48;
    int o0 = off[d];
    int deg = off[d + 1] - o0;
    float adm = a_dst[d * HH + hh];
    float m = lrelu(funmono(gmaxu[hh]) + adm);

    float den = 0.f;
    float acc[4] = {};
    int j = 0;
    for (; j + 4 <= deg; j += 4) {
        int s0 = csr_src[o0 + j + 0];
        int s1 = csr_src[o0 + j + 1];
        int s2 = csr_src[o0 + j + 2];
        int s3 = csr_src[o0 + j + 3];
        int ssel = s3;
        if (g == 0) ssel = s0; else if (g == 1) ssel = s1; else if (g == 2) ssel = s2;
        float e = __expf(lrelu(a_src[ssel * HH + hh] + adm) - m);
        float e0 = __shfl(e, gb + 0, 64);
        float e1 = __shfl(e, gb + 1, 64);
        float e2 = __shfl(e, gb + 2, 64);
        float e3 = __shfl(e, gb + 3, 64);
        den += (e0 + e1) + (e2 + e3);
        uint2 h0 = *(const uint2*)&Hb[(size_t)s0 * HC + lane * 4];
        uint2 h1 = *(const uint2*)&Hb[(size_t)s1 * HC + lane * 4];
        uint2 h2 = *(const uint2*)&Hb[(size_t)s2 * HC + lane * 4];
        uint2 h3 = *(const uint2*)&Hb[(size_t)s3 * HC + lane * 4];
        acc[0] += e0 * __uint_as_float(h0.x << 16) + e1 * __uint_as_float(h1.x << 16)
                + e2 * __uint_as_float(h2.x << 16) + e3 * __uint_as_float(h3.x << 16);
        acc[1] += e0 * __uint_as_float(h0.x & 0xffff0000u) + e1 * __uint_as_float(h1.x & 0xffff0000u)
                + e2 * __uint_as_float(h2.x & 0xffff0000u) + e3 * __uint_as_float(h3.x & 0xffff0000u);
        acc[2] += e0 * __uint_as_float(h0.y << 16) + e1 * __uint_as_float(h1.y << 16)
                + e2 * __uint_as_float(h2.y << 16) + e3 * __uint_as_float(h3.y << 16);
        acc[3] += e0 * __uint_as_float(h0.y & 0xffff0000u) + e1 * __uint_as_float(h1.y & 0xffff0000u)
                + e2 * __uint_as_float(h2.y & 0xffff0000u) + e3 * __uint_as_float(h3.y & 0xffff0000u);
    }
    for (; j < deg; j++) {
        int s = csr_src[o0 + j];
        float al = __expf(lrelu(a_src[s * HH + hh] + adm) - m);
        den += al;
        uint2 hv = *(const uint2*)&Hb[(size_t)s * HC + lane * 4];
        acc[0] += al * __uint_as_float(hv.x << 16);
        acc[1] += al * __uint_as_float(hv.x & 0xffff0000u);
        acc[2] += al * __uint_as_float(hv.y << 16);
        acc[3] += al * __uint_as_float(hv.y & 0xffff0000u);
    }
    float inv = 1.f / (den + 1e-16f);
    float4 bv = *(const float4*)&bias[lane * 4];
    float v0 = fmaxf(acc[0] * inv + bv.x, 0.f);
    float v1 = fmaxf(acc[1] * inv + bv.y, 0.f);
    float v2 = fmaxf(acc[2] * inv + bv.z, 0.f);
    float v3 = fmaxf(acc[3] * inv + bv.w, 0.f);
    uint2 o;
    o.x = (unsigned)f2b(v0) | ((unsigned)f2b(v1) << 16);
    o.y = (unsigned)f2b(v2) | ((unsigned)f2b(v3) << 16);
    *(uint2*)&outb16[(size_t)d * HC + lane * 4] = o;
}

// ---------------- layer-3 GAT edge pass (HC=64, 1 head): 4 edges per wave
// instruction, x2 unrolled, cross-group shfl_xor combine.
__global__ __launch_bounds__(256) void gat_aggr3_kernel(const int* __restrict__ off,
                                                        const int* __restrict__ csr_src,
                                                        const u16* __restrict__ Hb,
                                                        const float* __restrict__ a_src,
                                                        const float* __restrict__ a_dst,
                                                        const unsigned* __restrict__ gmaxu,
                                                        const float* __restrict__ bias,
                                                        float* __restrict__ outf32,
                                                        int n_nodes) {
    int d = blockIdx.x * 4 + (threadIdx.x >> 6);
    if (d >= n_nodes) return;
    int lane = threadIdx.x & 63;
    int grp = lane >> 4;
    int li = lane & 15;
    int o0 = off[d];
    int deg = off[d + 1] - o0;
    float adm = a_dst[d];
    float m = lrelu(funmono(gmaxu[0]) + adm);

    float den = 0.f;
    float a0 = 0.f, a1 = 0.f, a2 = 0.f, a3 = 0.f;
    int j = 0;
    for (; j + 8 <= deg; j += 8) {
        int sA = csr_src[o0 + j + grp];
        int sB = csr_src[o0 + j + 4 + grp];
        float alA = __expf(lrelu(a_src[sA] + adm) - m);
        float alB = __expf(lrelu(a_src[sB] + adm) - m);
        uint2 hA = *(const uint2*)&Hb[(size_t)sA * 64 + li * 4];
        uint2 hB = *(const uint2*)&Hb[(size_t)sB * 64 + li * 4];
        den += alA + alB;
        a0 += alA * __uint_as_float(hA.x << 16) + alB * __uint_as_float(hB.x << 16);
        a1 += alA * __uint_as_float(hA.x & 0xffff0000u) + alB * __uint_as_float(hB.x & 0xffff0000u);
        a2 += alA * __uint_as_float(hA.y << 16) + alB * __uint_as_float(hB.y << 16);
        a3 += alA * __uint_as_float(hA.y & 0xffff0000u) + alB * __uint_as_float(hB.y & 0xffff0000u);
    }
    for (; j < deg; j += 4) {
        int e = j + grp;
        float al = 0.f;
        unsigned hx = 0u, hy = 0u;
        if (e < deg) {
            int s = csr_src[o0 + e];
            al = __expf(lrelu(a_src[s] + adm) - m);
            uint2 hv = *(const uint2*)&Hb[(size_t)s * 64 + li * 4];
            hx = hv.x; hy = hv.y;
        }
        den += al;
        a0 += al * __uint_as_float(hx << 16);
        a1 += al * __uint_as_float(hx & 0xffff0000u);
        a2 += al * __uint_as_float(hy << 16);
        a3 += al * __uint_as_float(hy & 0xffff0000u);
    }
    #pragma unroll
    for (int o = 16; o < 64; o <<= 1) {
        den += __shfl_xor(den, o, 64);
        a0  += __shfl_xor(a0, o, 64);
        a1  += __shfl_xor(a1, o, 64);
        a2  += __shfl_xor(a2, o, 64);
        a3  += __shfl_xor(a3, o, 64);
    }
    if (grp == 0) {
        float inv = 1.f / (den + 1e-16f);
        float4 bv = *(const float4*)&bias[li * 4];
        float4 o;
        o.x = fmaxf(a0 * inv + bv.x, 0.f);
        o.y = fmaxf(a1 * inv + bv.y, 0.f);
        o.z = fmaxf(a2 * inv + bv.z, 0.f);
        o.w = fmaxf(a3 * inv + bv.w, 0.f);
        *(float4*)&outf32[(size_t)d * 64 + li * 4] = o;
    }
}

// ---------------- segment-sum pooling over sorted batch ids; lane = feature
__global__ __launch_bounds__(256) void pool_kernel(const float* __restrict__ H3,
                                                   const int* __restrict__ batch,
                                                   float* __restrict__ pooled, int n_nodes) {
    int wave = (blockIdx.x * 256 + threadIdx.x) >> 6;
    int lane = threadIdx.x & 63;
    int nwaves = gridDim.x * 4;
    int chunk = (n_nodes + nwaves - 1) / nwaves;
    int start = wave * chunk;
    int end = min(n_nodes, start + chunk);
    if (start >= end) return;
    int cur = batch[start];
    float acc = 0.f;
    for (int n = start; n < end; n++) {
        int g = batch[n];
        if (g != cur) { atomAddF(&pooled[cur * 64 + lane], acc); acc = 0.f; cur = g; }
        acc += H3[(size_t)n * 64 + lane];
    }
    atomAddF(&pooled[cur * 64 + lane], acc);
}

// ---------------- tiny MLP head
__global__ __launch_bounds__(64) void mlp_kernel(const float* __restrict__ pooled,
                                                 const float* __restrict__ Wm1,
                                                 const float* __restrict__ bm1,
                                                 const float* __restrict__ Wm2,
                                                 const float* __restrict__ bm2,
                                                 float* __restrict__ out) {
    __shared__ float sp[64], sh[64];
    int g = blockIdx.x, t = threadIdx.x;
    sp[t] = pooled[g * 64 + t];
    __syncthreads();
    float a = bm1[t];
    for (int k = 0; k < 64; k++) a += sp[k] * Wm1[k * 64 + t];
    sh[t] = a > 0.f ? a : 0.f;
    __syncthreads();
    if (t < 10) {
        float o = bm2[t];
        for (int j = 0; j < 64; j++) o += sh[j] * Wm2[j * 10 + t];
        out[g * 10 + t] = o;
    }
}

extern "C" void kernel_launch(void* const* d_in, const int* in_sizes, int n_in,
                              void* d_out, int out_size, void* d_ws, size_t ws_size,
                              hipStream_t stream) {
    const float* x   = (const float*)d_in[0];
    const int*   ei  = (const int*)d_in[1];
    const int*   bat = (const int*)d_in[2];
    const float* W1  = (const float*)d_in[3];
    const float* b1  = (const float*)d_in[4];
    const float* as1 = (const float*)d_in[5];
    const float* ad1 = (const float*)d_in[6];
    const float* W2  = (const float*)d_in[7];
    const float* b2  = (const float*)d_in[8];
    const float* as2 = (const float*)d_in[9];
    const float* ad2 = (const float*)d_in[10];
    const float* W3  = (const float*)d_in[11];
    const float* b3  = (const float*)d_in[12];
    const float* as3 = (const float*)d_in[13];
    const float* ad3 = (const float*)d_in[14];
    const float* Wm1 = (const float*)d_in[15];
    const float* bm1 = (const float*)d_in[16];
    const float* Wm2 = (const float*)d_in[17];
    const float* bm2 = (const float*)d_in[18];
    float* out = (float*)d_out;

    const int Nn = in_sizes[0] / F_IN;     // 50000
    const int Ee = in_sizes[1] / 2;        // 800000
    const int Et = Ee + Nn;

    // workspace layout
    char* wsp = (char*)d_ws;
    size_t off_b = 0;
    auto alloc = [&](size_t bytes) { void* p = wsp + off_b; off_b += (bytes + 255) & ~(size_t)255; return p; };
    u16*   HbA     = (u16*)alloc((size_t)Nn * 256 * 2);
    u16*   HbB     = (u16*)alloc((size_t)Nn * 256 * 2);
    float* Hf      = (float*)alloc((size_t)Nn * HID * 4);
    u16*   Wt1     = (u16*)alloc((size_t)256 * 128 * 2);
    u16*   Wt2     = (u16*)alloc((size_t)256 * 256 * 2);
    u16*   Wt3     = (u16*)alloc((size_t)64 * 256 * 2);
    float* a_src   = (float*)alloc((size_t)Nn * HEADS * 4);
    float* a_dst   = (float*)alloc((size_t)Nn * HEADS * 4);
    // one contiguous zeroed region: gmaxu(16) + deg(Nn) + cursor(Nn) + pooled(64*64)
    size_t zcount = 16 + (size_t)Nn * 2 + NGRP * HID;
    unsigned* zbase = (unsigned*)alloc(zcount * 4);
    unsigned* gmaxu = zbase;                    // 3 layers: +0,+4,+8
    int*   deg     = (int*)(zbase + 16);
    int*   cursor  = deg + Nn;
    float* pooled  = (float*)(cursor + Nn);
    int*   bsum    = (int*)alloc((size_t)256 * 4);
    int*   csr_off = (int*)alloc((size_t)(Nn + 1) * 4);
    int*   csr_src = (int*)alloc((size_t)Et * 4);
    (void)ws_size;

    // ---- one-time weight conversion (single kernel)
    wtrans_all_kernel<<<(114688 + 255) / 256, 256, 0, stream>>>(W1, W2, W3, Wt1, Wt2, Wt3);

    // ---- zero gmaxu/deg/cursor/pooled in one memset
    hipMemsetAsync(zbase, 0, zcount * 4, stream);

    // ---- CSR build (once, reused by all layers)
    int eb = (Et + 255) / 256;
    int nb = (Nn + 255) / 256;  // 196 <= 256
    count_kernel<<<eb, 256, 0, stream>>>(ei, deg, Ee, Nn);
    scan_reduce_kernel<<<nb, 256, 0, stream>>>(deg, bsum, Nn);
    scan_blocksums_kernel<<<1, 256, 0, stream>>>(bsum, nb);
    scan_final_kernel<<<nb, 256, 0, stream>>>(deg, bsum, csr_off, Nn);
    // range-partitioned fill (2 passes): active slice ~1.8 MB stays L2-resident
    {
        int q = (Nn + 1) / 2;
        for (int p = 0; p < 2; p++) {
            int lo = p * q, hi = min(Nn, lo + q);
            fill_part_kernel<<<eb, 256, 0, stream>>>(ei, csr_off, cursor, csr_src,
                                                     Ee, Nn, lo, hi);
        }
    }

    const int gemm_blocks = (Nn + 127) / 128;
    const int nodeBlocks = (Nn + 3) / 4;

    // ---- layer 1 (fp32 x staged+converted in GEMM)
    gemm_att_kernel<128, 256, true><<<gemm_blocks, 512, 0, stream>>>(x, Wt1, as1, ad1,
                                                                     HbA, a_src, a_dst, Nn);
    gmax_kernel<4><<<64, 256, 0, stream>>>(a_src, gmaxu + 0, Nn);
    gat_aggr_kernel<<<nodeBlocks, 256, 0, stream>>>(csr_off, csr_src, HbA,
                                                    a_src, a_dst, gmaxu + 0, b1, HbB, Nn);
    // ---- layer 2
    gemm_att_kernel<256, 256, false><<<gemm_blocks, 512, 0, stream>>>(HbB, Wt2, as2, ad2,
                                                                      HbA, a_src, a_dst, Nn);
    gmax_kernel<4><<<64, 256, 0, stream>>>(a_src, gmaxu + 4, Nn);
    gat_aggr_kernel<<<nodeBlocks, 256, 0, stream>>>(csr_off, csr_src, HbA,
                                                    a_src, a_dst, gmaxu + 4, b2, HbB, Nn);
    // ---- layer 3 (heads=1, out fp32 for pooling)
    gemm_att_kernel<256, 64, false><<<gemm_blocks, 512, 0, stream>>>(HbB, Wt3, as3, ad3,
                                                                     HbA, a_src, a_dst, Nn);
    gmax_kernel<1><<<64, 256, 0, stream>>>(a_src, gmaxu + 8, Nn);
    gat_aggr3_kernel<<<nodeBlocks, 256, 0, stream>>>(csr_off, csr_src, HbA,
                                                     a_src, a_dst, gmaxu + 8, b3, Hf, Nn);

    pool_kernel<<<128, 256, 0, stream>>>(Hf, bat, pooled, Nn);
    mlp_kernel<<<NGRP, 64, 0, stream>>>(pooled, Wm1, bm1, Wm2, bm2, out);
}